// Round 3
// baseline (2621.606 us; speedup 1.0000x reference)
//
#include <hip/hip_runtime.h>

#define HID 16
#define OUTC 4

// ---------- CSR build ----------
__global__ void k_hist(const int* __restrict__ dst, int* __restrict__ hist, int E) {
    for (int i = blockIdx.x * blockDim.x + threadIdx.x; i < E; i += gridDim.x * blockDim.x)
        atomicAdd(hist + dst[i], 1);
}

// per-256-chunk reduce -> bsum, plus dinv = rsqrt(deg+1)
__global__ void k_scan1(const int* __restrict__ hist, int* __restrict__ bsum,
                        float* __restrict__ dinv, int N) {
    __shared__ int s[256];
    int i = blockIdx.x * 256 + threadIdx.x;
    int v = (i < N) ? hist[i] : 0;
    if (i < N) dinv[i] = rsqrtf((float)v + 1.0f);   // +1 = self-loop, deg>0 always
    s[threadIdx.x] = v; __syncthreads();
    for (int off = 128; off > 0; off >>= 1) {
        if (threadIdx.x < off) s[threadIdx.x] += s[threadIdx.x + off];
        __syncthreads();
    }
    if (threadIdx.x == 0) bsum[blockIdx.x] = s[0];
}

// single-block exclusive scan of bsum (chunked with carry)
__global__ void k_scan2(int* __restrict__ bsum, int nb) {
    __shared__ int s[1024];
    int carry = 0;
    for (int base = 0; base < nb; base += 1024) {
        int idx = base + threadIdx.x;
        int v = (idx < nb) ? bsum[idx] : 0;
        s[threadIdx.x] = v; __syncthreads();
        for (int off = 1; off < 1024; off <<= 1) {
            int t = (threadIdx.x >= (unsigned)off) ? s[threadIdx.x - off] : 0;
            __syncthreads();
            s[threadIdx.x] += t;
            __syncthreads();
        }
        if (idx < nb) bsum[idx] = carry + s[threadIdx.x] - v;   // exclusive
        carry += s[1023];
        __syncthreads();
    }
}

// block-local exclusive scan + block offset -> row, cursor
__global__ void k_scan3(const int* __restrict__ hist, const int* __restrict__ boff,
                        int* __restrict__ row, int* __restrict__ cursor, int N, int E) {
    __shared__ int s[256];
    int i = blockIdx.x * 256 + threadIdx.x;
    int v = (i < N) ? hist[i] : 0;
    s[threadIdx.x] = v; __syncthreads();
    for (int off = 1; off < 256; off <<= 1) {
        int t = (threadIdx.x >= (unsigned)off) ? s[threadIdx.x - off] : 0;
        __syncthreads();
        s[threadIdx.x] += t;
        __syncthreads();
    }
    if (i < N) {
        int ex = boff[blockIdx.x] + s[threadIdx.x] - v;
        row[i] = ex; cursor[i] = ex;
    }
    if (i == 0) row[N] = E;
}

__global__ void k_scatter(const int* __restrict__ src, const int* __restrict__ dst,
                          int* __restrict__ cursor, int* __restrict__ csr, int E) {
    for (int i = blockIdx.x * blockDim.x + threadIdx.x; i < E; i += gridDim.x * blockDim.x) {
        int p = atomicAdd(cursor + dst[i], 1);
        csr[p] = src[i];
    }
}

// ---------- dense transforms ----------
// m1[n][c] = x[n] * W1[c]  (IN_C == 1)
__global__ void k_m1(const float* __restrict__ x, const float* __restrict__ W1,
                     float* __restrict__ m, int N) {
    int t = blockIdx.x * blockDim.x + threadIdx.x;
    if (t < N * HID) {
        int n = t >> 4, c = t & 15;
        m[t] = x[n] * W1[c];
    }
}

// m2[n][co] = sum_ci h[n][ci] * W2[ci][co]
__global__ void k_m2(const float* __restrict__ h, const float* __restrict__ W2,
                     float* __restrict__ m, int N) {
    __shared__ float w[HID * HID];
    if (threadIdx.x < HID * HID) w[threadIdx.x] = W2[threadIdx.x];
    __syncthreads();
    int t = blockIdx.x * blockDim.x + threadIdx.x;
    if (t < N * HID) {
        int n = t >> 4, co = t & 15;
        const float* hr = h + n * HID;
        float acc = 0.f;
#pragma unroll
        for (int ci = 0; ci < HID; ++ci) acc += hr[ci] * w[ci * HID + co];
        m[t] = acc;
    }
}

// ---------- CSR gather layers ----------
// 4 threads per node, float4 channel-quad per thread. h = relu(agg*dinv[n] + m[n]*dinv[n]^2 + b)
__global__ void k_gather_h(const int* __restrict__ row, const int* __restrict__ csr,
                           const float* __restrict__ dinv, const float4* __restrict__ m4,
                           const float4* __restrict__ b4, float4* __restrict__ h4, int N) {
    int n = blockIdx.x * 64 + (threadIdx.x >> 2);
    int c4 = threadIdx.x & 3;
    if (n >= N) return;
    float4 acc = make_float4(0.f, 0.f, 0.f, 0.f);
    int beg = row[n], end = row[n + 1];
    for (int i = beg; i < end; ++i) {
        int s = csr[i];
        float dv = dinv[s];
        float4 mv = m4[s * 4 + c4];
        acc.x += mv.x * dv; acc.y += mv.y * dv;
        acc.z += mv.z * dv; acc.w += mv.w * dv;
    }
    float dn = dinv[n];
    float dn2 = dn * dn;
    float4 mm = m4[n * 4 + c4];
    float4 bb = b4[c4];
    float4 r;
    r.x = acc.x * dn + mm.x * dn2 + bb.x;
    r.y = acc.y * dn + mm.y * dn2 + bb.y;
    r.z = acc.z * dn + mm.z * dn2 + bb.z;
    r.w = acc.w * dn + mm.w * dn2 + bb.w;
    r.x = r.x > 0.f ? r.x : 0.f;
    r.y = r.y > 0.f ? r.y : 0.f;
    r.z = r.z > 0.f ? r.z : 0.f;
    r.w = r.w > 0.f ? r.w : 0.f;
    h4[n * 4 + c4] = r;
}

// layer-2 gather fused with readout: out[n] = relu_h2[n] @ Wl + bl
__global__ void k_gather_out(const int* __restrict__ row, const int* __restrict__ csr,
                             const float* __restrict__ dinv, const float4* __restrict__ m4,
                             const float4* __restrict__ b4, const float* __restrict__ Wl,
                             const float* __restrict__ bl, float* __restrict__ out, int N) {
    __shared__ float hs[64][HID + 1];
    __shared__ float wl[HID * OUTC];
    if (threadIdx.x < HID * OUTC) wl[threadIdx.x] = Wl[threadIdx.x];
    int ln = threadIdx.x >> 2;
    int c4 = threadIdx.x & 3;
    int n = blockIdx.x * 64 + ln;
    if (n < N) {
        float4 acc = make_float4(0.f, 0.f, 0.f, 0.f);
        int beg = row[n], end = row[n + 1];
        for (int i = beg; i < end; ++i) {
            int s = csr[i];
            float dv = dinv[s];
            float4 mv = m4[s * 4 + c4];
            acc.x += mv.x * dv; acc.y += mv.y * dv;
            acc.z += mv.z * dv; acc.w += mv.w * dv;
        }
        float dn = dinv[n];
        float dn2 = dn * dn;
        float4 mm = m4[n * 4 + c4];
        float4 bb = b4[c4];
        float4 r;
        r.x = acc.x * dn + mm.x * dn2 + bb.x;
        r.y = acc.y * dn + mm.y * dn2 + bb.y;
        r.z = acc.z * dn + mm.z * dn2 + bb.z;
        r.w = acc.w * dn + mm.w * dn2 + bb.w;
        hs[ln][c4 * 4 + 0] = r.x > 0.f ? r.x : 0.f;
        hs[ln][c4 * 4 + 1] = r.y > 0.f ? r.y : 0.f;
        hs[ln][c4 * 4 + 2] = r.z > 0.f ? r.z : 0.f;
        hs[ln][c4 * 4 + 3] = r.w > 0.f ? r.w : 0.f;
    }
    __syncthreads();
    // readout: same 256 threads -> (node ln, out-channel c4)
    if (n < N) {
        float acc = bl[c4];
#pragma unroll
        for (int ci = 0; ci < HID; ++ci) acc += hs[ln][ci] * wl[ci * OUTC + c4];
        out[n * OUTC + c4] = acc;
    }
}

// ---------- launch ----------
static inline size_t alignup(size_t v, size_t a) { return (v + a - 1) & ~(a - 1); }

extern "C" void kernel_launch(void* const* d_in, const int* in_sizes, int n_in,
                              void* d_out, int out_size, void* d_ws, size_t ws_size,
                              hipStream_t stream) {
    const float* x  = (const float*)d_in[0];
    const int* ed   = (const int*)d_in[1];     // int inputs delivered as int32
    const float* W1 = (const float*)d_in[2];
    const float* b1 = (const float*)d_in[3];
    const float* W2 = (const float*)d_in[4];
    const float* b2 = (const float*)d_in[5];
    const float* Wl = (const float*)d_in[6];
    const float* bl = (const float*)d_in[7];
    float* out      = (float*)d_out;

    int N = in_sizes[0];
    int E = in_sizes[1] / 2;
    const int* src = ed;
    const int* dst = ed + E;
    int nb = (N + 255) / 256;

    // workspace layout (16B-aligned slices)
    char* w = (char*)d_ws;
    size_t o = 0;
    int* hist    = (int*)(w + o); o = alignup(o + (size_t)N * 4, 16);
    int* bsum    = (int*)(w + o); o = alignup(o + (size_t)nb * 4, 16);
    int* row     = (int*)(w + o); o = alignup(o + ((size_t)N + 1) * 4, 16);
    int* cursor  = (int*)(w + o); o = alignup(o + (size_t)N * 4, 16);
    int* csr     = (int*)(w + o); o = alignup(o + (size_t)E * 4, 16);
    float* dinv  = (float*)(w + o); o = alignup(o + (size_t)N * 4, 16);
    float* bufA  = (float*)(w + o); o = alignup(o + (size_t)N * HID * 4, 16);
    float* bufB  = (float*)(w + o); o = alignup(o + (size_t)N * HID * 4, 16);
    (void)ws_size;

    int blk = 256;
    int gN16 = (N * HID + blk - 1) / blk;

    // CSR build (also produces dinv)
    hipMemsetAsync(hist, 0, (size_t)N * 4, stream);
    k_hist<<<8192, blk, 0, stream>>>(dst, hist, E);
    k_scan1<<<nb, 256, 0, stream>>>(hist, bsum, dinv, N);
    k_scan2<<<1, 1024, 0, stream>>>(bsum, nb);
    k_scan3<<<nb, 256, 0, stream>>>(hist, bsum, row, cursor, N, E);
    k_scatter<<<8192, blk, 0, stream>>>(src, dst, cursor, csr, E);

    // layer 1: m1 -> gather(+relu+bias)
    k_m1<<<gN16, blk, 0, stream>>>(x, W1, bufA, N);
    k_gather_h<<<(N + 63) / 64, 256, 0, stream>>>(row, csr, dinv, (const float4*)bufA,
                                                  (const float4*)b1, (float4*)bufB, N);

    // layer 2: m2 -> gather fused with readout
    k_m2<<<gN16, blk, 0, stream>>>(bufB, W2, bufA, N);
    k_gather_out<<<(N + 63) / 64, 256, 0, stream>>>(row, csr, dinv, (const float4*)bufA,
                                                    (const float4*)b2, Wl, bl, out, N);
}